// Round 2
// baseline (11564.578 us; speedup 1.0000x reference)
//
#include <hip/hip_runtime.h>
#include <hip/hip_bf16.h>

#define LEAKY(v) ((v) >= 0.0f ? (v) : 0.01f * (v))

// ---------------------------------------------------------------------------
// k_init: copy ego -> x workspace (f32, row stride 64) and -> out cols [0,64)
// (f32, row stride 176). Works in float4 quanta: n*16 items.
// ---------------------------------------------------------------------------
__global__ void k_init(const float* __restrict__ ego, float* __restrict__ x,
                       float* __restrict__ out, int n) {
  int tid = blockIdx.x * blockDim.x + threadIdx.x;
  int total = n * 16;  // float4s per row: 64/4
  int stride = gridDim.x * blockDim.x;
  for (int t = tid; t < total; t += stride) {
    int r = t >> 4;
    int c = (t & 15) * 4;
    float4 v = *(const float4*)(ego + (size_t)r * 64 + c);
    *(float4*)(x + (size_t)r * 64 + c) = v;
    *(float4*)(out + (size_t)r * 176 + c) = v;
  }
}

// ---------------------------------------------------------------------------
// k_spmm: side[row] += val * x[col].  x has fixed row stride 64 (cols < DIN
// valid); side is packed with row stride DIN.  DIN/4 threads per edge, each
// thread does one float4 gather + 4 f32 atomics.
// ---------------------------------------------------------------------------
template <int DIN>
__global__ void k_spmm(const int* __restrict__ erow, const int* __restrict__ ecol,
                       const float* __restrict__ ev, const float* __restrict__ x,
                       float* side, int E) {
  constexpr int TPE = DIN / 4;               // threads per edge (16 or 8)
  constexpr int SH = (DIN == 64) ? 4 : 3;    // log2(TPE)
  long long tid = (long long)blockIdx.x * blockDim.x + threadIdx.x;
  long long total = (long long)E * TPE;
  long long stride = (long long)gridDim.x * blockDim.x;
  for (long long t = tid; t < total; t += stride) {
    int e = (int)(t >> SH);
    int i = ((int)t & (TPE - 1)) * 4;
    int r = erow[e];
    int c = ecol[e];
    float v = ev[e];
    float4 xv = *(const float4*)(x + (size_t)c * 64 + i);
    float* dst = side + (size_t)r * DIN + i;
    atomicAdd(dst + 0, v * xv.x);
    atomicAdd(dst + 1, v * xv.y);
    atomicAdd(dst + 2, v * xv.z);
    atomicAdd(dst + 3, v * xv.w);
  }
}

// ---------------------------------------------------------------------------
// k_xform: per row r (one wave64 each):
//   a = x[r] + side[r]; m = x[r] * side[r]
//   xn = leaky(a @ W1 + b1) + leaky(m @ W2 + b2)
//   x[r, 0:DOUT] = xn (in place, stride 64); out[r, col0:col0+DOUT] = l2n(xn)
// W1/W2/b staged in LDS (padded so lanes >= DOUT read in-bounds garbage).
// NOTE: x is read AND written (in place) -> no __restrict__ on it.
// ---------------------------------------------------------------------------
template <int DIN, int DOUT>
__global__ void __launch_bounds__(256) k_xform(
    float* x, const float* __restrict__ side,
    const float* __restrict__ W1, const float* __restrict__ b1,
    const float* __restrict__ W2, const float* __restrict__ b2,
    float* __restrict__ out, int out_col0, int n) {
  __shared__ float sW1[DIN * DOUT + 64];
  __shared__ float sW2[DIN * DOUT + 64];
  __shared__ float sb[128];
  for (int i = threadIdx.x; i < DIN * DOUT + 64; i += blockDim.x) {
    sW1[i] = (i < DIN * DOUT) ? W1[i] : 0.0f;
    sW2[i] = (i < DIN * DOUT) ? W2[i] : 0.0f;
  }
  for (int i = threadIdx.x; i < 64; i += blockDim.x) {
    sb[i] = (i < DOUT) ? b1[i] : 0.0f;
    sb[64 + i] = (i < DOUT) ? b2[i] : 0.0f;
  }
  __syncthreads();

  int row = (int)((blockIdx.x * (unsigned)blockDim.x + threadIdx.x) >> 6);
  int lane = threadIdx.x & 63;
  if (row >= n) return;

  float xv = 0.0f, sv = 0.0f;
  if (lane < DIN) {
    xv = x[(size_t)row * 64 + lane];
    sv = side[(size_t)row * DIN + lane];
  }
  float a = xv + sv;
  float m = xv * sv;

  float acc1 = sb[lane];
  float acc2 = sb[64 + lane];
#pragma unroll
  for (int k = 0; k < DIN; ++k) {
    float ak = __shfl(a, k);
    float mk = __shfl(m, k);
    acc1 = fmaf(ak, sW1[k * DOUT + lane], acc1);
    acc2 = fmaf(mk, sW2[k * DOUT + lane], acc2);
  }

  float s1 = LEAKY(acc1);
  float s2 = LEAKY(acc2);
  float xn = s1 + s2;

  float sq = (lane < DOUT) ? xn * xn : 0.0f;
#pragma unroll
  for (int off = 32; off > 0; off >>= 1) sq += __shfl_xor(sq, off);
  float inv = 1.0f / fmaxf(sqrtf(sq), 1e-12f);

  if (lane < DOUT) {
    x[(size_t)row * 64 + lane] = xn;
    out[(size_t)row * 176 + out_col0 + lane] = xn * inv;
  }
}

// ---------------------------------------------------------------------------
extern "C" void kernel_launch(void* const* d_in, const int* in_sizes, int n_in,
                              void* d_out, int out_size, void* d_ws, size_t ws_size,
                              hipStream_t stream) {
  const float* ego = (const float*)d_in[0];
  const int* erow = (const int*)d_in[1];
  const int* ecol = (const int*)d_in[2];
  const float* ev = (const float*)d_in[3];
  const int n = in_sizes[0] / 64;   // 160000
  const int E = in_sizes[1];        // 5120000

  float* x = (float*)d_ws;                       // [n, 64] f32
  float* side = x + (size_t)n * 64;              // [n, <=64] f32 (packed per layer)
  float* out = (float*)d_out;                    // [n, 176] f32

  k_init<<<2048, 256, 0, stream>>>(ego, x, out, n);

  const int xblocks = (n + 3) / 4;  // 4 waves (rows) per 256-thread block

  // ---- layer 0: 64 -> 64 ----
  hipMemsetAsync(side, 0, (size_t)n * 64 * sizeof(float), stream);
  k_spmm<64><<<8192, 256, 0, stream>>>(erow, ecol, ev, x, side, E);
  k_xform<64, 64><<<xblocks, 256, 0, stream>>>(
      x, side, (const float*)d_in[4], (const float*)d_in[5],
      (const float*)d_in[6], (const float*)d_in[7], out, 64, n);

  // ---- layer 1: 64 -> 32 ----
  hipMemsetAsync(side, 0, (size_t)n * 64 * sizeof(float), stream);
  k_spmm<64><<<8192, 256, 0, stream>>>(erow, ecol, ev, x, side, E);
  k_xform<64, 32><<<xblocks, 256, 0, stream>>>(
      x, side, (const float*)d_in[8], (const float*)d_in[9],
      (const float*)d_in[10], (const float*)d_in[11], out, 128, n);

  // ---- layer 2: 32 -> 16 ----
  hipMemsetAsync(side, 0, (size_t)n * 32 * sizeof(float), stream);
  k_spmm<32><<<8192, 256, 0, stream>>>(erow, ecol, ev, x, side, E);
  k_xform<32, 16><<<xblocks, 256, 0, stream>>>(
      x, side, (const float*)d_in[12], (const float*)d_in[13],
      (const float*)d_in[14], (const float*)d_in[15], out, 160, n);
}

// Round 4
// 2532.811 us; speedup vs baseline: 4.5659x; 4.5659x over previous
//
#include <hip/hip_runtime.h>
#include <hip/hip_bf16.h>

#define LEAKY(v) ((v) >= 0.0f ? (v) : 0.01f * (v))

// ---------------------------------------------------------------------------
// k_init: ego -> out cols [0,64) (raw, also serves as layer-0 input).
// ---------------------------------------------------------------------------
__global__ void k_init(const float* __restrict__ ego, float* __restrict__ out, int n) {
  int tid = blockIdx.x * blockDim.x + threadIdx.x;
  int total = n * 16;
  int stride = gridDim.x * blockDim.x;
  for (int t = tid; t < total; t += stride) {
    int r = t >> 4, c = (t & 15) * 4;
    float4 v = *(const float4*)(ego + (size_t)r * 64 + c);
    *(float4*)(out + (size_t)r * 176 + c) = v;
  }
}

// ---------------------------------------------------------------------------
// CSR build: histogram -> single-block scan -> scatter (col,val as int2)
// ---------------------------------------------------------------------------
__global__ void k_count(const int* __restrict__ erow, int* __restrict__ cnt, int E) {
  int tid = blockIdx.x * blockDim.x + threadIdx.x;
  int stride = gridDim.x * blockDim.x;
  for (int e = tid; e < E; e += stride) atomicAdd(&cnt[erow[e]], 1);
}

__global__ void __launch_bounds__(1024) k_scan(const int* __restrict__ cnt,
                                               int* __restrict__ rp,
                                               int* __restrict__ cur, int n) {
  __shared__ int ssum[1024];
  int t = threadIdx.x;
  int chunk = (n + 1023) >> 10;
  int beg = t * chunk;
  int end = min(beg + chunk, n);
  int s = 0;
  for (int i = beg; i < end; ++i) s += cnt[i];
  ssum[t] = s;
  __syncthreads();
  for (int off = 1; off < 1024; off <<= 1) {
    int v = (t >= off) ? ssum[t - off] : 0;
    __syncthreads();
    ssum[t] += v;
    __syncthreads();
  }
  int excl = (t == 0) ? 0 : ssum[t - 1];
  for (int i = beg; i < end; ++i) {
    rp[i] = excl;
    cur[i] = excl;
    excl += cnt[i];
  }
  if (t == 1023) rp[n] = excl;
}

__global__ void k_scatter(const int* __restrict__ erow, const int* __restrict__ ecol,
                          const float* __restrict__ ev, int* cur,
                          int2* __restrict__ cv, int E) {
  int tid = blockIdx.x * blockDim.x + threadIdx.x;
  int stride = gridDim.x * blockDim.x;
  for (int e = tid; e < E; e += stride) {
    int r = erow[e];
    int pos = atomicAdd(&cur[r], 1);
    int2 p;
    p.x = ecol[e];
    p.y = __float_as_int(ev[e]);
    cv[pos] = p;
  }
}

// ---------------------------------------------------------------------------
// k_spmm_csr: one wave per row, scalar edge loop (uniform cv load broadcast),
// lane = feature. xin points at the input column block (stride 176).
// DIN==32: both wave halves duplicate work; only lanes<DIN write.
// ---------------------------------------------------------------------------
template <int DIN>
__global__ void __launch_bounds__(256) k_spmm_csr(
    const int* __restrict__ rp, const int2* __restrict__ cv,
    const float* __restrict__ xin, float* __restrict__ side, int n) {
  int row = (int)((blockIdx.x * (unsigned)blockDim.x + threadIdx.x) >> 6);
  int lane = threadIdx.x & 63;
  if (row >= n) return;
  int f = lane & (DIN - 1);
  int beg = rp[row], end = rp[row + 1];
  float acc = 0.0f;
  int e = beg;
  for (; e + 2 <= end; e += 2) {
    int2 p0 = cv[e], p1 = cv[e + 1];
    acc = fmaf(__int_as_float(p0.y), xin[(size_t)p0.x * 176 + f], acc);
    acc = fmaf(__int_as_float(p1.y), xin[(size_t)p1.x * 176 + f], acc);
  }
  if (e < end) {
    int2 p = cv[e];
    acc = fmaf(__int_as_float(p.y), xin[(size_t)p.x * 176 + f], acc);
  }
  if (lane < DIN) side[(size_t)row * DIN + lane] = acc;
}

// ---------------------------------------------------------------------------
// Fallback SpMM (atomic scatter, round-2 proven): xin stride 176.
// ---------------------------------------------------------------------------
template <int DIN>
__global__ void k_spmm_at(const int* __restrict__ erow, const int* __restrict__ ecol,
                          const float* __restrict__ ev, const float* __restrict__ xin,
                          float* side, int E) {
  constexpr int TPE = DIN / 4;
  constexpr int SH = (DIN == 64) ? 4 : 3;
  long long tid = (long long)blockIdx.x * blockDim.x + threadIdx.x;
  long long total = (long long)E * TPE;
  long long stride = (long long)gridDim.x * blockDim.x;
  for (long long t = tid; t < total; t += stride) {
    int e = (int)(t >> SH);
    int i = ((int)t & (TPE - 1)) * 4;
    int r = erow[e], c = ecol[e];
    float v = ev[e];
    float4 xv = *(const float4*)(xin + (size_t)c * 176 + i);
    float* dst = side + (size_t)r * DIN + i;
    atomicAdd(dst + 0, v * xv.x);
    atomicAdd(dst + 1, v * xv.y);
    atomicAdd(dst + 2, v * xv.z);
    atomicAdd(dst + 3, v * xv.w);
  }
}

// ---------------------------------------------------------------------------
// k_xform: round-2's verbatim-passing transform. One wave per row.
// Reads xin (stride 176) + side (stride DIN); writes UNNORMALIZED xn to
// outp (stride 176). xin/outp alias the out buffer -> no __restrict__.
// ---------------------------------------------------------------------------
template <int DIN, int DOUT>
__global__ void __launch_bounds__(256) k_xform(
    const float* xin, const float* __restrict__ side,
    const float* __restrict__ W1, const float* __restrict__ b1,
    const float* __restrict__ W2, const float* __restrict__ b2,
    float* outp, int n) {
  __shared__ float sW1[DIN * DOUT + 64];
  __shared__ float sW2[DIN * DOUT + 64];
  __shared__ float sb[128];
  for (int i = threadIdx.x; i < DIN * DOUT + 64; i += blockDim.x) {
    sW1[i] = (i < DIN * DOUT) ? W1[i] : 0.0f;
    sW2[i] = (i < DIN * DOUT) ? W2[i] : 0.0f;
  }
  for (int i = threadIdx.x; i < 64; i += blockDim.x) {
    sb[i] = (i < DOUT) ? b1[i] : 0.0f;
    sb[64 + i] = (i < DOUT) ? b2[i] : 0.0f;
  }
  __syncthreads();

  int row = (int)((blockIdx.x * (unsigned)blockDim.x + threadIdx.x) >> 6);
  int lane = threadIdx.x & 63;
  if (row >= n) return;

  float xv = 0.0f, sv = 0.0f;
  if (lane < DIN) {
    xv = xin[(size_t)row * 176 + lane];
    sv = side[(size_t)row * DIN + lane];
  }
  float a = xv + sv;
  float m = xv * sv;

  float acc1 = sb[lane], acc2 = sb[64 + lane];
#pragma unroll
  for (int k = 0; k < DIN; ++k) {
    float ak = __shfl(a, k), mk = __shfl(m, k);
    acc1 = fmaf(ak, sW1[k * DOUT + lane], acc1);
    acc2 = fmaf(mk, sW2[k * DOUT + lane], acc2);
  }
  float xn = LEAKY(acc1) + LEAKY(acc2);
  if (lane < DOUT) outp[(size_t)row * 176 + lane] = xn;
}

// ---------------------------------------------------------------------------
// k_norm: final pass, L2-normalize cols [64,128), [128,160), [160,176) in
// place. One wave per row.
// ---------------------------------------------------------------------------
__global__ void __launch_bounds__(256) k_norm(float* out, int n) {
  int row = (int)((blockIdx.x * (unsigned)blockDim.x + threadIdx.x) >> 6);
  int lane = threadIdx.x & 63;
  if (row >= n) return;
  float* r = out + (size_t)row * 176;
  float a = r[64 + lane];
  float b = (lane < 48) ? r[128 + lane] : 0.0f;
  float sa = a * a;
  float sb_ = (lane < 32) ? b * b : 0.0f;
  float sc = (lane >= 32 && lane < 48) ? b * b : 0.0f;
#pragma unroll
  for (int off = 32; off; off >>= 1) {
    sa += __shfl_xor(sa, off);
    sb_ += __shfl_xor(sb_, off);
    sc += __shfl_xor(sc, off);
  }
  float ia = 1.0f / fmaxf(sqrtf(sa), 1e-12f);
  float ib = 1.0f / fmaxf(sqrtf(sb_), 1e-12f);
  float ic = 1.0f / fmaxf(sqrtf(sc), 1e-12f);
  r[64 + lane] = a * ia;
  if (lane < 48) r[128 + lane] = b * ((lane < 32) ? ib : ic);
}

// ---------------------------------------------------------------------------
extern "C" void kernel_launch(void* const* d_in, const int* in_sizes, int n_in,
                              void* d_out, int out_size, void* d_ws, size_t ws_size,
                              hipStream_t stream) {
  const float* ego = (const float*)d_in[0];
  const int* erow = (const int*)d_in[1];
  const int* ecol = (const int*)d_in[2];
  const float* ev = (const float*)d_in[3];
  const int n = in_sizes[0] / 64;  // 160000
  const int E = in_sizes[1];       // 5120000

  float* out = (float*)d_out;  // [n, 176] f32

  // ws layout (CSR path): rp[n+1] | side[n*64] | cv[E] | cnt[n] | cur[n]
  int* rp = (int*)d_ws;
  float* side = (float*)(rp + n + 1);
  int2* cv = (int2*)(side + (size_t)n * 64);
  int* cnt = (int*)(cv + E);
  int* cur = cnt + n;
  size_t need_csr = (size_t)(n + 1) * 4 + (size_t)n * 64 * 4 + (size_t)E * 8 +
                    (size_t)n * 4 * 2;
  bool use_csr = ws_size >= need_csr;

  const int rblocks = (n + 3) / 4;  // one wave per row, 4 waves/block

  k_init<<<2048, 256, 0, stream>>>(ego, out, n);

  if (use_csr) {
    hipMemsetAsync(cnt, 0, (size_t)n * sizeof(int), stream);
    k_count<<<2048, 256, 0, stream>>>(erow, cnt, E);
    k_scan<<<1, 1024, 0, stream>>>(cnt, rp, cur, n);
    k_scatter<<<2048, 256, 0, stream>>>(erow, ecol, ev, cur, cv, E);

    k_spmm_csr<64><<<rblocks, 256, 0, stream>>>(rp, cv, out, side, n);
    k_xform<64, 64><<<rblocks, 256, 0, stream>>>(
        out, side, (const float*)d_in[4], (const float*)d_in[5],
        (const float*)d_in[6], (const float*)d_in[7], out + 64, n);

    k_spmm_csr<64><<<rblocks, 256, 0, stream>>>(rp, cv, out + 64, side, n);
    k_xform<64, 32><<<rblocks, 256, 0, stream>>>(
        out + 64, side, (const float*)d_in[8], (const float*)d_in[9],
        (const float*)d_in[10], (const float*)d_in[11], out + 128, n);

    k_spmm_csr<32><<<rblocks, 256, 0, stream>>>(rp, cv, out + 128, side, n);
    k_xform<32, 16><<<rblocks, 256, 0, stream>>>(
        out + 128, side, (const float*)d_in[12], (const float*)d_in[13],
        (const float*)d_in[14], (const float*)d_in[15], out + 160, n);
  } else {
    // fallback: atomic-scatter SpMM (round-2 proven), side at ws start
    float* sideA = (float*)d_ws;

    hipMemsetAsync(sideA, 0, (size_t)n * 64 * sizeof(float), stream);
    k_spmm_at<64><<<8192, 256, 0, stream>>>(erow, ecol, ev, out, sideA, E);
    k_xform<64, 64><<<rblocks, 256, 0, stream>>>(
        out, sideA, (const float*)d_in[4], (const float*)d_in[5],
        (const float*)d_in[6], (const float*)d_in[7], out + 64, n);

    hipMemsetAsync(sideA, 0, (size_t)n * 64 * sizeof(float), stream);
    k_spmm_at<64><<<8192, 256, 0, stream>>>(erow, ecol, ev, out + 64, sideA, E);
    k_xform<64, 32><<<rblocks, 256, 0, stream>>>(
        out + 64, sideA, (const float*)d_in[8], (const float*)d_in[9],
        (const float*)d_in[10], (const float*)d_in[11], out + 128, n);

    hipMemsetAsync(sideA, 0, (size_t)n * 32 * sizeof(float), stream);
    k_spmm_at<32><<<8192, 256, 0, stream>>>(erow, ecol, ev, out + 128, sideA, E);
    k_xform<32, 16><<<rblocks, 256, 0, stream>>>(
        out + 128, sideA, (const float*)d_in[12], (const float*)d_in[13],
        (const float*)d_in[14], (const float*)d_in[15], out + 160, n);
  }

  k_norm<<<rblocks, 256, 0, stream>>>(out, n);
}